// Round 7
// baseline (608.443 us; speedup 1.0000x reference)
//
#include <hip/hip_runtime.h>

// Problem constants
#define B_   2
#define NQ_  8192
#define NK_  8192
#define DIN_ 256
#define DH_  256
#define M_   (B_ * NQ_)   // 16384 flattened rows

typedef _Float16 f16x8 __attribute__((ext_vector_type(8)));
typedef unsigned short u16x8 __attribute__((ext_vector_type(8)));
typedef unsigned short u16x4 __attribute__((ext_vector_type(4)));
typedef unsigned int  u32x4 __attribute__((ext_vector_type(4)));
typedef float f32x16 __attribute__((ext_vector_type(16)));

// fp32 -> fp16 bits (RTNE via hardware cvt)
__device__ __forceinline__ unsigned short f2h(float f) {
    _Float16 h = (_Float16)f;
    return __builtin_bit_cast(unsigned short, h);
}
__device__ __forceinline__ float h2f(unsigned short u) {
    return (float)__builtin_bit_cast(_Float16, u);
}

// ---------------------------------------------------------------------------
// Kernel 1: weight convert + repack into MFMA B-fragment order (unchanged v7).
// wpack[mat][ks][ng][lane][j] = fp16(W[k = ks*16 + (lane>>5)*8 + j]
//                                    [n = ng*32 + (lane&31)])
// ---------------------------------------------------------------------------
__global__ void wt_conv(const float* __restrict__ Wq, const float* __restrict__ Wk,
                        const float* __restrict__ Wv, unsigned short* __restrict__ wpack) {
    __shared__ float tile[64][65];
    const int mat = blockIdx.z;
    const int k0 = blockIdx.x * 64, n0 = blockIdx.y * 64;
    const float* W = (mat == 0) ? Wq : (mat == 1) ? Wk : Wv;
#pragma unroll
    for (int p = 0; p < 16; ++p) {
        const int idx = p * 256 + threadIdx.x;
        const int r = idx >> 6, c = idx & 63;    // r = kk, c = nn
        tile[r][c] = W[(k0 + r) * 256 + n0 + c];
    }
    __syncthreads();
    unsigned short* wp = wpack + mat * 65536;
#pragma unroll
    for (int p = 0; p < 2; ++p) {
        const int e = p * 256 + threadIdx.x;     // 0..511
        const int kk8 = e >> 6;                  // 8-k group 0..7
        const int nn = e & 63;
        const int ks = (k0 >> 4) + (kk8 >> 1);
        const int lh = kk8 & 1;
        const int ng = (n0 >> 5) + (nn >> 5);
        const int l = (nn & 31) + 32 * lh;
        u16x8 val;
#pragma unroll
        for (int j = 0; j < 8; ++j) val[j] = f2h(tile[kk8 * 8 + j][nn]);
        *(u16x8*)(wp + ((size_t)(ks * 8 + ng) * 64 + l) * 8) = val;
    }
}

// ---------------------------------------------------------------------------
// Kernel 2: projections v7 (unchanged — proven).
// ---------------------------------------------------------------------------
__global__ __launch_bounds__(256) void proj(
    const float* __restrict__ xq, const float* __restrict__ xk, const float* __restrict__ xv,
    const float* __restrict__ bq, const float* __restrict__ bk, const float* __restrict__ bv,
    const unsigned short* __restrict__ wpack,
    unsigned short* __restrict__ q_emb, unsigned short* __restrict__ k_emb,
    unsigned short* __restrict__ vpack) {
    __shared__ __align__(16) unsigned short xt[64 * 256];   // 32 KB fp16, swizzled
    const int mat = blockIdx.y;
    const float* x    = (mat == 0) ? xq : (mat == 1) ? xk : xv;
    const float* bias = (mat == 0) ? bq : (mat == 1) ? bk : bv;
    const unsigned short* wp = wpack + mat * 65536;

    const int tid = threadIdx.x;
    const int l = tid & 63, wv = tid >> 6;
    const int pair = wv >> 1, h = wv & 1;
    const int lm = l & 31, lh = l >> 5;
    const int row0 = blockIdx.x * 64;

    {
        const float* xb = x + (size_t)row0 * 256;
#pragma unroll
        for (int p = 0; p < 8; ++p) {
            const int idx = p * 256 + tid;       // 0..2047
            const int r = idx >> 5;              // row 0..63
            const int c8 = idx & 31;             // granule 0..31
            const float4* ap = (const float4*)(xb + r * 256 + c8 * 8);
            float4 a0 = ap[0], a1 = ap[1];
            u16x8 au;
            au[0] = f2h(a0.x); au[1] = f2h(a0.y); au[2] = f2h(a0.z); au[3] = f2h(a0.w);
            au[4] = f2h(a1.x); au[5] = f2h(a1.y); au[6] = f2h(a1.z); au[7] = f2h(a1.w);
            *(u16x8*)(xt + r * 256 + (c8 ^ (r & 31)) * 8) = au;
        }
    }
    __syncthreads();

    f32x16 acc[4];
#pragma unroll
    for (int i = 0; i < 4; ++i)
#pragma unroll
        for (int j = 0; j < 16; ++j) acc[i][j] = 0.0f;

#pragma unroll
    for (int ks = 0; ks < 16; ++ks) {
        f16x8 af = *(const f16x8*)(xt + (pair * 32 + lm) * 256 +
                                   (((ks * 2 + lh) ^ lm) * 8));
#pragma unroll
        for (int nt = 0; nt < 4; ++nt) {
            f16x8 bfr = *(const f16x8*)(wp + ((size_t)(ks * 8 + h * 4 + nt) * 64 + l) * 8);
            acc[nt] = __builtin_amdgcn_mfma_f32_32x32x16_f16(af, bfr, acc[nt], 0, 0, 0);
        }
    }

    if (mat < 2) {
        unsigned short* emb = (mat == 0) ? q_emb : k_emb;
#pragma unroll
        for (int nt = 0; nt < 4; ++nt) {
            const int n = h * 128 + nt * 32 + lm;
            const float bsv = bias[n];
#pragma unroll
            for (int r = 0; r < 16; ++r) {
                const int rl = (r & 3) + 8 * (r >> 2) + 4 * lh;
                emb[(size_t)(row0 + pair * 32 + rl) * 256 + n] = f2h(acc[nt][r] + bsv);
            }
        }
    } else {
        const int batch = row0 >> 13;
        const int m0 = (row0 & 8191) + pair * 32;   // v-row (k index) base
        unsigned short* vp = vpack + (size_t)batch * (512 * 8 * 64 * 8);
        const int base_kt = m0 >> 4;
#pragma unroll
        for (int nt = 0; nt < 4; ++nt) {
            const int dg = h * 4 + nt;              // d-group = n >> 5
            const int n = h * 128 + nt * 32 + lm;
            const float bsv = bias[n];
#pragma unroll
            for (int g = 0; g < 4; ++g) {
                u16x4 pk;
#pragma unroll
                for (int i = 0; i < 4; ++i) pk[i] = f2h(acc[nt][4 * g + i] + bsv);
                const int kt = base_kt + (g >> 1);
                const int lane = (g & 1) * 32 + lm;
                *(u16x4*)(vp + ((size_t)(kt * 8 + dg) * 64 + lane) * 8 + lh * 4) = pk;
            }
        }
    }
}

// ---------------------------------------------------------------------------
// Kernel 3: flash attention v8 — 2 blocks/CU producer-consumer.
//   512 blocks x 256 threads (4 waves).  Block owns 32 q rows; BN=64.
//   Waves 0-1 (S-waves, kq=wv): QK^T S^T tile (32k x 32q each) + softmax;
//   Waves 2-3 (PV-waves, pw=wv&1): own d-groups pw*4..pw*4+3, consume the
//   PREVIOUS tile's P (double-buffered pbuf) while S(t) computes.
//   PV-waves re-derive alpha/l from smax/ssum (same values S-waves use ->
//   numerically identical chains).  K via global_load_lds dbuf (source-side
//   XOR granule swizzle, proven).  V via vpack fragments (proven).
//   2 __syncthreads per iter:
//     B3: smax[t] visible to S-waves' exp phase (and K-DMA drain).
//     B4: pbuf[t]/ssum[t] visible for next iter's PV; drains next-K DMA + vf.
//   Hazards: all producer->consumer flows are parity-split dbufs; K-dbuf WAR
//   separated by B3(t-1)..issue(t); DMA visibility via B4 vmcnt(0).
//   LDS 74 KB -> 2 blocks/CU (two independent barrier groups per CU).
// ---------------------------------------------------------------------------
#define BN6_ 64
#define NT6_ (NK_ / BN6_)                  // 128 iterations
#define KTILE_B 32768                      // 64 rows x 512B (swizzled granules)
#define PST6 144                           // 32 rows x (128 + 16) : 9 granules, odd
#define PBUF_OFF (2 * KTILE_B)             // 65536
#define SMAX_OFF (PBUF_OFF + 2 * 32 * PST6)  // 74752
#define SSUM_OFF (SMAX_OFF + 512)          // 75264
#define LDS6_TOTAL (SSUM_OFF + 512)        // 75776 <= 80 KiB

__global__ __launch_bounds__(256, 2) void flash(
    const unsigned short* __restrict__ q_emb, const unsigned short* __restrict__ k_emb,
    const unsigned short* __restrict__ vpack, float* __restrict__ out) {
    __shared__ __align__(16) char lds_raw[LDS6_TOTAL];
    char* pb = lds_raw + PBUF_OFF;              // [2][32][144]
    float* smax = (float*)(lds_raw + SMAX_OFF); // [2][32][2]
    float* ssum = (float*)(lds_raw + SSUM_OFF); // [2][32][2]

    const int tid = threadIdx.x;
    const int l = tid & 63, wv = tid >> 6;      // wv 0..3
    const int lm = l & 31, lh = l >> 5;
    const bool is_s = (wv < 2);
    const int kq = wv & 1;                      // S-wave k-tile (0..1)
    const int pw = wv & 1;                      // PV-wave d-half (0..1)

    const int bx = blockIdx.x;
    const int batch = bx >> 8;                  // 512 blocks: 256 per batch
    const int qb = (bx & 255) * 32;

    const unsigned short* kg = k_emb + (size_t)batch * NK_ * 256;
    const unsigned short* vp = vpack + (size_t)batch * (512 * 8 * 64 * 8);

    // ---- K staging via global_load_lds: 4 waves cover 64 rows (8 instr/wave).
    // LDS[r][g] = global[r][g ^ (r&31)]; dest linear, swizzle on SOURCE.
    const int rlane = l >> 5;
    const int gl = l & 31;
    auto stage_k = [&](int kb, char* kdst) {
#pragma unroll
        for (int p = 0; p < 8; ++p) {
            const int r0 = wv * 16 + 2 * p;            // wave-uniform base row
            const int r = r0 + rlane;
            const int gsw = gl ^ (r & 31);
            const unsigned short* src = kg + (size_t)(kb + r) * 256 + gsw * 8;
            __builtin_amdgcn_global_load_lds(
                (const __attribute__((address_space(1))) void*)src,
                (__attribute__((address_space(3))) void*)(kdst + r0 * 512),
                16, 0, 0);
        }
    };

    // ---- per-role persistent state ----
    f16x8 qf[16];                 // S-waves: Q row q = qb + lm, 256 dims
    float mstat_s = -3.0e38f;
    f16x8 vf[16];                 // PV-waves: frag (kt, dg=pw*4+dgi) for tile t
    f32x16 oacc[4];               // PV-waves: O^T[d = (pw*4+dgi)*32+crow][q=lm]
    float mstat_p = -3.0e38f, lstat = 0.0f;

    if (is_s) {
        const int mrow = batch * NQ_ + qb + lm;
#pragma unroll
        for (int ks = 0; ks < 16; ++ks)
            qf[ks] = *(const f16x8*)(q_emb + (size_t)mrow * 256 + ks * 16 + lh * 8);
    } else {
#pragma unroll
        for (int i = 0; i < 4; ++i)
#pragma unroll
            for (int j = 0; j < 16; ++j) oacc[i][j] = 0.0f;
    }

    // prologue: K tile 0
    stage_k(0, lds_raw);
    __syncthreads();   // vmcnt(0) drain -> K tile 0 visible

    for (int t = 0; t < NT6_; ++t) {
        const int kb = t * BN6_;
        if (t + 1 < NT6_) stage_k(kb + BN6_, lds_raw + ((t + 1) & 1) * KTILE_B);

        f32x16 s;   // S-waves' score tile (lives across B3)
        if (is_s) {
            // ---- S(t): 32k x 32q, A = K rows kq*32+lm (swizzled), B = qf ----
            char* kcur = lds_raw + (t & 1) * KTILE_B;
#pragma unroll
            for (int j = 0; j < 16; ++j) s[j] = 0.0f;
#pragma unroll
            for (int ks = 0; ks < 16; ++ks) {
                const int gsw = (2 * ks + lh) ^ lm;
                f16x8 kf = *(const f16x8*)(kcur + (kq * 32 + lm) * 512 + gsw * 16);
                s = __builtin_amdgcn_mfma_f32_32x32x16_f16(kf, qf[ks], s, 0, 0, 0);
            }
            float pm = s[0];
#pragma unroll
            for (int j = 1; j < 16; ++j) pm = fmaxf(pm, s[j]);
            pm = fmaxf(pm, __shfl_xor(pm, 32, 64));
            if (lh == 0) smax[(t & 1) * 64 + lm * 2 + kq] = pm;
        } else {
            // ---- PV(t-1): rescale + O^T += V^T P^T from pbuf[(t-1)&1] ----
            if (t > 0) {
                const int pp = (t - 1) & 1;
                const float m0 = smax[pp * 64 + lm * 2 + 0];
                const float m1 = smax[pp * 64 + lm * 2 + 1];
                const float gm = fmaxf(m0, m1);
                const float mn = fmaxf(mstat_p, gm);
                const float alpha = __expf(mstat_p - mn);
                mstat_p = mn;
                const float s0 = ssum[pp * 64 + lm * 2 + 0];
                const float s1 = ssum[pp * 64 + lm * 2 + 1];
                lstat = lstat * alpha + (s0 + s1);
#pragma unroll
                for (int dgi = 0; dgi < 4; ++dgi)
#pragma unroll
                    for (int j = 0; j < 16; ++j) oacc[dgi][j] *= alpha;
                char* pbr = pb + pp * 32 * PST6;
#pragma unroll
                for (int ks2 = 0; ks2 < 4; ++ks2) {
                    f16x8 pf = *(const f16x8*)(pbr + lm * PST6 + ks2 * 32 + lh * 16);
#pragma unroll
                    for (int dgi = 0; dgi < 4; ++dgi)
                        oacc[dgi] = __builtin_amdgcn_mfma_f32_32x32x16_f16(
                            vf[ks2 * 4 + dgi], pf, oacc[dgi], 0, 0, 0);
                }
            }
            // ---- prefetch vf for tile t (used next iter; drained at B4) ----
            const size_t kt0 = (size_t)(kb >> 4);
#pragma unroll
            for (int ks2 = 0; ks2 < 4; ++ks2)
#pragma unroll
                for (int dgi = 0; dgi < 4; ++dgi)
                    vf[ks2 * 4 + dgi] = *(const f16x8*)(
                        vp + (((kt0 + ks2) * 8 + pw * 4 + dgi) * 64 + l) * 8);
        }
        __syncthreads();   // B3: smax[t] visible (also drains K-DMA, vf)

        if (is_s) {
            // ---- exp (fp16-rounded), write P^T into pbuf[t&1], psum ----
            const float m0 = smax[(t & 1) * 64 + lm * 2 + 0];
            const float m1 = smax[(t & 1) * 64 + lm * 2 + 1];
            const float gm = fmaxf(m0, m1);
            const float mn = fmaxf(mstat_s, gm);
            mstat_s = mn;
            char* pbw = pb + (t & 1) * 32 * PST6;
            float psum = 0.0f;
#pragma unroll
            for (int g = 0; g < 4; ++g) {
                u16x4 pk;
#pragma unroll
                for (int j = 0; j < 4; ++j) {
                    const unsigned short hh = f2h(__expf(s[g * 4 + j] - mn));
                    pk[j] = hh;
                    psum += h2f(hh);
                }
                *(u16x4*)(pbw + lm * PST6 + kq * 64 + 16 * g + 8 * lh) = pk;
            }
            psum += __shfl_xor(psum, 32, 64);
            if (lh == 0) ssum[(t & 1) * 64 + lm * 2 + kq] = psum;
        }
        __syncthreads();   // B4: pbuf[t]/ssum[t] visible; next-K DMA drained
    }

    // ---- epilogue: PV(NT-1) + output (PV-waves only) ----
    if (!is_s) {
        const int pp = (NT6_ - 1) & 1;
        const float m0 = smax[pp * 64 + lm * 2 + 0];
        const float m1 = smax[pp * 64 + lm * 2 + 1];
        const float gm = fmaxf(m0, m1);
        const float mn = fmaxf(mstat_p, gm);
        const float alpha = __expf(mstat_p - mn);
        mstat_p = mn;
        const float s0 = ssum[pp * 64 + lm * 2 + 0];
        const float s1 = ssum[pp * 64 + lm * 2 + 1];
        lstat = lstat * alpha + (s0 + s1);
#pragma unroll
        for (int dgi = 0; dgi < 4; ++dgi)
#pragma unroll
            for (int j = 0; j < 16; ++j) oacc[dgi][j] *= alpha;
        char* pbr = pb + pp * 32 * PST6;
#pragma unroll
        for (int ks2 = 0; ks2 < 4; ++ks2) {
            f16x8 pf = *(const f16x8*)(pbr + lm * PST6 + ks2 * 32 + lh * 16);
#pragma unroll
            for (int dgi = 0; dgi < 4; ++dgi)
                oacc[dgi] = __builtin_amdgcn_mfma_f32_32x32x16_f16(
                    vf[ks2 * 4 + dgi], pf, oacc[dgi], 0, 0, 0);
        }

        const float linv = 1.0f / lstat;
        float* orow = out + (size_t)(batch * NQ_ + qb + lm) * 256;
#pragma unroll
        for (int dgi = 0; dgi < 4; ++dgi) {
            const int d0 = (pw * 4 + dgi) * 32;
#pragma unroll
            for (int g = 0; g < 4; ++g) {
                float4 o4;
                o4.x = oacc[dgi][4 * g + 0] * linv;
                o4.y = oacc[dgi][4 * g + 1] * linv;
                o4.z = oacc[dgi][4 * g + 2] * linv;
                o4.w = oacc[dgi][4 * g + 3] * linv;
                *(float4*)(orow + d0 + 8 * g + 4 * lh) = o4;
            }
        }
    }
}

// ---------------------------------------------------------------------------
extern "C" void kernel_launch(void* const* d_in, const int* in_sizes, int n_in,
                              void* d_out, int out_size, void* d_ws, size_t ws_size,
                              hipStream_t stream) {
    const float* q  = (const float*)d_in[0];
    const float* k  = (const float*)d_in[1];
    const float* v  = (const float*)d_in[2];
    const float* Wq = (const float*)d_in[3];
    const float* bq = (const float*)d_in[4];
    const float* Wk = (const float*)d_in[5];
    const float* bk = (const float*)d_in[6];
    const float* Wv = (const float*)d_in[7];
    const float* bv = (const float*)d_in[8];
    float* out = (float*)d_out;

    unsigned short* wpack   = (unsigned short*)d_ws;          // 3 * 65536 fp16
    unsigned short* q_emb   = wpack + 3 * 65536;              // [16384][256]
    unsigned short* k_emb   = q_emb + (size_t)M_ * DH_;       // [16384][256]
    unsigned short* vpack   = k_emb + (size_t)M_ * DH_;       // [2][512][8][64][8]

    wt_conv<<<dim3(4, 4, 3), 256, 0, stream>>>(Wq, Wk, Wv, wpack);
    proj<<<dim3(256, 3), 256, 0, stream>>>(q, k, v, bq, bk, bv, wpack, q_emb, k_emb, vpack);
    flash<<<512, 256, 0, stream>>>(q_emb, k_emb, vpack, out);
}

// Round 8
// 296.046 us; speedup vs baseline: 2.0552x; 2.0552x over previous
//
#include <hip/hip_runtime.h>

// Problem constants
#define B_   2
#define NQ_  8192
#define NK_  8192
#define DIN_ 256
#define DH_  256
#define M_   (B_ * NQ_)   // 16384 flattened rows

typedef _Float16 f16x8 __attribute__((ext_vector_type(8)));
typedef unsigned short u16x8 __attribute__((ext_vector_type(8)));
typedef unsigned short u16x4 __attribute__((ext_vector_type(4)));
typedef unsigned int  u32x4 __attribute__((ext_vector_type(4)));
typedef float f32x16 __attribute__((ext_vector_type(16)));

// fp32 -> fp16 bits (RTNE via hardware cvt)
__device__ __forceinline__ unsigned short f2h(float f) {
    _Float16 h = (_Float16)f;
    return __builtin_bit_cast(unsigned short, h);
}
__device__ __forceinline__ float h2f(unsigned short u) {
    return (float)__builtin_bit_cast(_Float16, u);
}

// ---------------------------------------------------------------------------
// Kernel 1: weight convert + repack into MFMA B-fragment order (proven v7).
// wpack[mat][ks][ng][lane][j] = fp16(W[k = ks*16 + (lane>>5)*8 + j]
//                                    [n = ng*32 + (lane&31)])
// ---------------------------------------------------------------------------
__global__ void wt_conv(const float* __restrict__ Wq, const float* __restrict__ Wk,
                        const float* __restrict__ Wv, unsigned short* __restrict__ wpack) {
    __shared__ float tile[64][65];
    const int mat = blockIdx.z;
    const int k0 = blockIdx.x * 64, n0 = blockIdx.y * 64;
    const float* W = (mat == 0) ? Wq : (mat == 1) ? Wk : Wv;
#pragma unroll
    for (int p = 0; p < 16; ++p) {
        const int idx = p * 256 + threadIdx.x;
        const int r = idx >> 6, c = idx & 63;    // r = kk, c = nn
        tile[r][c] = W[(k0 + r) * 256 + n0 + c];
    }
    __syncthreads();
    unsigned short* wp = wpack + mat * 65536;
#pragma unroll
    for (int p = 0; p < 2; ++p) {
        const int e = p * 256 + threadIdx.x;     // 0..511
        const int kk8 = e >> 6;                  // 8-k group 0..7
        const int nn = e & 63;
        const int ks = (k0 >> 4) + (kk8 >> 1);
        const int lh = kk8 & 1;
        const int ng = (n0 >> 5) + (nn >> 5);
        const int l = (nn & 31) + 32 * lh;
        u16x8 val;
#pragma unroll
        for (int j = 0; j < 8; ++j) val[j] = f2h(tile[kk8 * 8 + j][nn]);
        *(u16x8*)(wp + ((size_t)(ks * 8 + ng) * 64 + l) * 8) = val;
    }
}

// ---------------------------------------------------------------------------
// Kernel 2: projections v7 (unchanged — proven).
// ---------------------------------------------------------------------------
__global__ __launch_bounds__(256) void proj(
    const float* __restrict__ xq, const float* __restrict__ xk, const float* __restrict__ xv,
    const float* __restrict__ bq, const float* __restrict__ bk, const float* __restrict__ bv,
    const unsigned short* __restrict__ wpack,
    unsigned short* __restrict__ q_emb, unsigned short* __restrict__ k_emb,
    unsigned short* __restrict__ vpack) {
    __shared__ __align__(16) unsigned short xt[64 * 256];   // 32 KB fp16, swizzled
    const int mat = blockIdx.y;
    const float* x    = (mat == 0) ? xq : (mat == 1) ? xk : xv;
    const float* bias = (mat == 0) ? bq : (mat == 1) ? bk : bv;
    const unsigned short* wp = wpack + mat * 65536;

    const int tid = threadIdx.x;
    const int l = tid & 63, wv = tid >> 6;
    const int pair = wv >> 1, h = wv & 1;
    const int lm = l & 31, lh = l >> 5;
    const int row0 = blockIdx.x * 64;

    {
        const float* xb = x + (size_t)row0 * 256;
#pragma unroll
        for (int p = 0; p < 8; ++p) {
            const int idx = p * 256 + tid;       // 0..2047
            const int r = idx >> 5;              // row 0..63
            const int c8 = idx & 31;             // granule 0..31
            const float4* ap = (const float4*)(xb + r * 256 + c8 * 8);
            float4 a0 = ap[0], a1 = ap[1];
            u16x8 au;
            au[0] = f2h(a0.x); au[1] = f2h(a0.y); au[2] = f2h(a0.z); au[3] = f2h(a0.w);
            au[4] = f2h(a1.x); au[5] = f2h(a1.y); au[6] = f2h(a1.z); au[7] = f2h(a1.w);
            *(u16x8*)(xt + r * 256 + (c8 ^ (r & 31)) * 8) = au;
        }
    }
    __syncthreads();

    f32x16 acc[4];
#pragma unroll
    for (int i = 0; i < 4; ++i)
#pragma unroll
        for (int j = 0; j < 16; ++j) acc[i][j] = 0.0f;

#pragma unroll
    for (int ks = 0; ks < 16; ++ks) {
        f16x8 af = *(const f16x8*)(xt + (pair * 32 + lm) * 256 +
                                   (((ks * 2 + lh) ^ lm) * 8));
#pragma unroll
        for (int nt = 0; nt < 4; ++nt) {
            f16x8 bfr = *(const f16x8*)(wp + ((size_t)(ks * 8 + h * 4 + nt) * 64 + l) * 8);
            acc[nt] = __builtin_amdgcn_mfma_f32_32x32x16_f16(af, bfr, acc[nt], 0, 0, 0);
        }
    }

    if (mat < 2) {
        unsigned short* emb = (mat == 0) ? q_emb : k_emb;
#pragma unroll
        for (int nt = 0; nt < 4; ++nt) {
            const int n = h * 128 + nt * 32 + lm;
            const float bsv = bias[n];
#pragma unroll
            for (int r = 0; r < 16; ++r) {
                const int rl = (r & 3) + 8 * (r >> 2) + 4 * lh;
                emb[(size_t)(row0 + pair * 32 + rl) * 256 + n] = f2h(acc[nt][r] + bsv);
            }
        }
    } else {
        const int batch = row0 >> 13;
        const int m0 = (row0 & 8191) + pair * 32;   // v-row (k index) base
        unsigned short* vp = vpack + (size_t)batch * (512 * 8 * 64 * 8);
        const int base_kt = m0 >> 4;
#pragma unroll
        for (int nt = 0; nt < 4; ++nt) {
            const int dg = h * 4 + nt;              // d-group = n >> 5
            const int n = h * 128 + nt * 32 + lm;
            const float bsv = bias[n];
#pragma unroll
            for (int g = 0; g < 4; ++g) {
                u16x4 pk;
#pragma unroll
                for (int i = 0; i < 4; ++i) pk[i] = f2h(acc[nt][4 * g + i] + bsv);
                const int kt = base_kt + (g >> 1);
                const int lane = (g & 1) * 32 + lm;
                *(u16x4*)(vp + ((size_t)(kt * 8 + dg) * 64 + lane) * 8 + lh * 4) = pk;
            }
        }
    }
}

// ---------------------------------------------------------------------------
// Kernel 3: flash attention v9 = proven v6/v7 structure (193 us) +
//   (a) defer-max THR=8: keep old running max while tile-max growth <= 8;
//       alpha == 1.0 exactly then, and the 32-mul O rescale is skipped under
//       a wave-uniform __any branch.  P bounded by e^8 (fp16-safe), psum/l
//       in fp32; num/denom consistency preserved.
//   (b) tree-shaped 16-way max (depth 4 vs chain 15; fmax is associative).
// Everything else byte-identical to the 193 us kernel.
// ---------------------------------------------------------------------------
#define BN_ 128
#define NT_ (NK_ / BN_)                    // 64 iterations
#define KB_BYTES 65536                     // 128 rows x 512B (swizzled granules)
#define PSTRIDE 272                        // 64 rows x (256 + 16) : proven pad
#define PBYTES  (64 * PSTRIDE)             // 17408
#define STAT_OFF (2 * KB_BYTES + PBYTES)   // 148480
#define LDS_TOTAL (STAT_OFF + 2048)        // 150528 <= 160 KiB

__global__ __launch_bounds__(512, 2) void flash(
    const unsigned short* __restrict__ q_emb, const unsigned short* __restrict__ k_emb,
    const unsigned short* __restrict__ vpack, float* __restrict__ out) {
    __shared__ __align__(16) char lds_raw[LDS_TOTAL];
    char* pbuf = lds_raw + 2 * KB_BYTES;        // [64][272]
    float* smax = (float*)(lds_raw + STAT_OFF); // [64][4]
    float* ssum = smax + 256;                   // [64][4]
    float* alph = ssum + 256;                   // [64] per-q-row alpha
    float* linvb = alph + 64;                   // [64] per-q-row 1/l

    const int tid = threadIdx.x;
    const int l = tid & 63, wv = tid >> 6;      // wv 0..7
    const int kq = wv >> 1, pair = wv & 1;      // S-phase roles
    const int lm = l & 31, lh = l >> 5;

    const int bx = blockIdx.x;
    const int batch = bx >> 7;
    const int qb = (bx & 127) * 64;

    const unsigned short* kg = k_emb + (size_t)batch * NK_ * 256;
    const unsigned short* vp = vpack + (size_t)batch * (512 * 8 * 64 * 8);

    // Q fragments register-resident: q row = qb + pair*32 + lm, all 256 dims.
    const int mrow = batch * NQ_ + qb + pair * 32 + lm;
    f16x8 qf[16];
#pragma unroll
    for (int ks = 0; ks < 16; ++ks)
        qf[ks] = *(const f16x8*)(q_emb + (size_t)mrow * 256 + ks * 16 + lh * 8);

    // O^T accumulator (PV role): d rows = wv*32 + crow, q cols = qt*32 + lm.
    f32x16 oacc[2];
#pragma unroll
    for (int i = 0; i < 2; ++i)
#pragma unroll
        for (int j = 0; j < 16; ++j) oacc[i][j] = 0.0f;

    float mstat = -3.0e38f, lstat = 0.0f;

    // ---- K staging via global_load_lds ----
    const int rlane = l >> 5;                  // +0/+1 row within 1KB chunk
    const int gl = l & 31;                     // linear granule this lane fills
    auto stage_k = [&](int kb, char* kdst) {
#pragma unroll
        for (int p = 0; p < 8; ++p) {
            const int r0 = wv * 16 + 2 * p;            // wave-uniform base row
            const int r = r0 + rlane;
            const int gsw = gl ^ (r & 31);             // source granule
            const unsigned short* src = kg + (size_t)(kb + r) * 256 + gsw * 8;
            __builtin_amdgcn_global_load_lds(
                (const __attribute__((address_space(1))) void*)src,
                (__attribute__((address_space(3))) void*)(kdst + r0 * 512),
                16, 0, 0);
        }
    };

    // ---- V fragments direct-from-global, DEDUPED: dg = wv, 8 frags/wave.
    f16x8 vf[8];
    auto load_v = [&](int kb) {
        const size_t kt0 = (size_t)(kb >> 4);
#pragma unroll
        for (int ks2 = 0; ks2 < 8; ++ks2)
            vf[ks2] = *(const f16x8*)(vp + (((kt0 + ks2) * 8 + wv) * 64 + l) * 8);
    };

    // prologue: K tile 0 (full drain once)
    stage_k(0, lds_raw);
    __syncthreads();   // vmcnt(0) drain -> K tile 0 visible

    const int prow = pair * 32 + lm;  // this lane's S-role q row within block

    for (int t = 0; t < NT_; ++t) {
        const int kb = t * BN_;
        char* kcur = lds_raw + (t & 1) * KB_BYTES;
        // issue DMA for next K tile, then this tile's vf loads
        if (t + 1 < NT_) stage_k(kb + BN_, lds_raw + ((t + 1) & 1) * KB_BYTES);
        load_v(kb);

        // ---- S^T tile (32k x 32q): A = K rows kq*32+lm (swizzled), B = qf ----
        f32x16 s;
#pragma unroll
        for (int j = 0; j < 16; ++j) s[j] = 0.0f;
#pragma unroll
        for (int ks = 0; ks < 16; ++ks) {
            const int gsw = (2 * ks + lh) ^ lm;   // 32 lanes -> 32 distinct granules
            f16x8 kf = *(const f16x8*)(kcur + (kq * 32 + lm) * 512 + gsw * 16);
            s = __builtin_amdgcn_mfma_f32_32x32x16_f16(kf, qf[ks], s, 0, 0, 0);
        }

        // ---- partial max over this wave's 32 k (tree reduce, per lane q=lm) ----
        float t0 = fmaxf(s[0], s[1]),  t1 = fmaxf(s[2], s[3]);
        float t2 = fmaxf(s[4], s[5]),  t3 = fmaxf(s[6], s[7]);
        float t4 = fmaxf(s[8], s[9]),  t5 = fmaxf(s[10], s[11]);
        float t6 = fmaxf(s[12], s[13]), t7 = fmaxf(s[14], s[15]);
        float u0 = fmaxf(t0, t1), u1 = fmaxf(t2, t3);
        float u2 = fmaxf(t4, t5), u3 = fmaxf(t6, t7);
        float pm = fmaxf(fmaxf(u0, u1), fmaxf(u2, u3));
        pm = fmaxf(pm, __shfl_xor(pm, 32, 64));
        if (lh == 0) smax[prow * 4 + kq] = pm;
        __syncthreads();   // B3: partial maxes visible

        const float4 m4 = *(const float4*)&smax[prow * 4];
        const float gm = fmaxf(fmaxf(m4.x, m4.y), fmaxf(m4.z, m4.w));
        // ---- defer-max: only advance m when growth exceeds THR=8 ----
        const bool upd = gm > mstat + 8.0f;
        const float mn = upd ? fmaxf(mstat, gm) : mstat;
        const float alpha = upd ? __expf(mstat - mn) : 1.0f;
        mstat = mn;
        if (kq == 0 && lh == 0) alph[prow] = alpha;   // publish per-q-row alpha

        // ---- exp (fp16-rounded for num/denom consistency), write P^T tile,
        //      partial sum ----
        float psum = 0.0f;
#pragma unroll
        for (int g = 0; g < 4; ++g) {
            u16x4 pk;
#pragma unroll
            for (int j = 0; j < 4; ++j) {
                const unsigned short hh = f2h(__expf(s[g * 4 + j] - mn));
                pk[j] = hh;
                psum += h2f(hh);
            }
            *(u16x4*)(pbuf + prow * PSTRIDE + (kq * 32 + 8 * g + 4 * lh) * 2) = pk;
        }
        psum += __shfl_xor(psum, 32, 64);
        if (lh == 0) ssum[prow * 4 + kq] = psum;
        __syncthreads();   // B4: P tiles + partial sums + alph visible

        const float4 s4 = *(const float4*)&ssum[prow * 4];
        lstat = lstat * alpha + (s4.x + s4.y) + (s4.z + s4.w);

        // ---- rescale O by per-q-row alpha; skip when tile was deferred
        //      (alpha == 1.0 exactly for every row then) ----
        const float a0 = alph[lm];
        const float a1 = alph[lm + 32];
        if (__any((a0 != 1.0f) || (a1 != 1.0f))) {
#pragma unroll
            for (int j = 0; j < 16; ++j) oacc[0][j] *= a0;
#pragma unroll
            for (int j = 0; j < 16; ++j) oacc[1][j] *= a1;
        }

        // ---- O^T += V^T P^T : A = vf (dg = wv, registers), B = P frags for
        //      both q-tiles from LDS ----
#pragma unroll
        for (int ks2 = 0; ks2 < 8; ++ks2) {
            const f16x8 vfr = vf[ks2];
            f16x8 pf0 = *(const f16x8*)(pbuf + lm * PSTRIDE + ks2 * 32 + lh * 16);
            f16x8 pf1 = *(const f16x8*)(pbuf + (lm + 32) * PSTRIDE + ks2 * 32 + lh * 16);
            oacc[0] = __builtin_amdgcn_mfma_f32_32x32x16_f16(vfr, pf0, oacc[0], 0, 0, 0);
            oacc[1] = __builtin_amdgcn_mfma_f32_32x32x16_f16(vfr, pf1, oacc[1], 0, 0, 0);
        }
    }

    // ---- publish per-q-row 1/l, then write out[b][q][d] fp32 ----
    if (kq == 0 && lh == 0) linvb[prow] = 1.0f / lstat;
    __syncthreads();
    const float linv0 = linvb[lm];
    const float linv1 = linvb[lm + 32];
#pragma unroll
    for (int qt = 0; qt < 2; ++qt) {
        const float lv = qt ? linv1 : linv0;
        float* orow = out + (size_t)(batch * NQ_ + qb + qt * 32 + lm) * 256 + wv * 32;
#pragma unroll
        for (int g = 0; g < 4; ++g) {
            float4 o4;
            o4.x = oacc[qt][4 * g + 0] * lv;
            o4.y = oacc[qt][4 * g + 1] * lv;
            o4.z = oacc[qt][4 * g + 2] * lv;
            o4.w = oacc[qt][4 * g + 3] * lv;
            *(float4*)(orow + 8 * g + 4 * lh) = o4;
        }
    }
}

// ---------------------------------------------------------------------------
extern "C" void kernel_launch(void* const* d_in, const int* in_sizes, int n_in,
                              void* d_out, int out_size, void* d_ws, size_t ws_size,
                              hipStream_t stream) {
    const float* q  = (const float*)d_in[0];
    const float* k  = (const float*)d_in[1];
    const float* v  = (const float*)d_in[2];
    const float* Wq = (const float*)d_in[3];
    const float* bq = (const float*)d_in[4];
    const float* Wk = (const float*)d_in[5];
    const float* bk = (const float*)d_in[6];
    const float* Wv = (const float*)d_in[7];
    const float* bv = (const float*)d_in[8];
    float* out = (float*)d_out;

    unsigned short* wpack   = (unsigned short*)d_ws;          // 3 * 65536 fp16
    unsigned short* q_emb   = wpack + 3 * 65536;              // [16384][256]
    unsigned short* k_emb   = q_emb + (size_t)M_ * DH_;       // [16384][256]
    unsigned short* vpack   = k_emb + (size_t)M_ * DH_;       // [2][512][8][64][8]

    wt_conv<<<dim3(4, 4, 3), 256, 0, stream>>>(Wq, Wk, Wv, wpack);
    proj<<<dim3(256, 3), 256, 0, stream>>>(q, k, v, bq, bk, bv, wpack, q_emb, k_emb, vpack);
    flash<<<256, 512, 0, stream>>>(q_emb, k_emb, vpack, out);
}

// Round 9
// 288.665 us; speedup vs baseline: 2.1078x; 1.0256x over previous
//
#include <hip/hip_runtime.h>

// Problem constants
#define B_   2
#define NQ_  8192
#define NK_  8192
#define DIN_ 256
#define DH_  256
#define M_   (B_ * NQ_)   // 16384 flattened rows

typedef _Float16 f16x8 __attribute__((ext_vector_type(8)));
typedef unsigned short u16x8 __attribute__((ext_vector_type(8)));
typedef unsigned short u16x4 __attribute__((ext_vector_type(4)));
typedef unsigned int  u32x4 __attribute__((ext_vector_type(4)));
typedef float f32x16 __attribute__((ext_vector_type(16)));

// fp32 -> fp16 bits (RTNE via hardware cvt)
__device__ __forceinline__ unsigned short f2h(float f) {
    _Float16 h = (_Float16)f;
    return __builtin_bit_cast(unsigned short, h);
}
__device__ __forceinline__ float h2f(unsigned short u) {
    return (float)__builtin_bit_cast(_Float16, u);
}

// ---------------------------------------------------------------------------
// Kernel 1: weight convert + repack into MFMA B-fragment order (proven v7).
// wpack[mat][ks][ng][lane][j] = fp16(W[k = ks*16 + (lane>>5)*8 + j]
//                                    [n = ng*32 + (lane&31)])
// ---------------------------------------------------------------------------
__global__ void wt_conv(const float* __restrict__ Wq, const float* __restrict__ Wk,
                        const float* __restrict__ Wv, unsigned short* __restrict__ wpack) {
    __shared__ float tile[64][65];
    const int mat = blockIdx.z;
    const int k0 = blockIdx.x * 64, n0 = blockIdx.y * 64;
    const float* W = (mat == 0) ? Wq : (mat == 1) ? Wk : Wv;
#pragma unroll
    for (int p = 0; p < 16; ++p) {
        const int idx = p * 256 + threadIdx.x;
        const int r = idx >> 6, c = idx & 63;    // r = kk, c = nn
        tile[r][c] = W[(k0 + r) * 256 + n0 + c];
    }
    __syncthreads();
    unsigned short* wp = wpack + mat * 65536;
#pragma unroll
    for (int p = 0; p < 2; ++p) {
        const int e = p * 256 + threadIdx.x;     // 0..511
        const int kk8 = e >> 6;                  // 8-k group 0..7
        const int nn = e & 63;
        const int ks = (k0 >> 4) + (kk8 >> 1);
        const int lh = kk8 & 1;
        const int ng = (n0 >> 5) + (nn >> 5);
        const int l = (nn & 31) + 32 * lh;
        u16x8 val;
#pragma unroll
        for (int j = 0; j < 8; ++j) val[j] = f2h(tile[kk8 * 8 + j][nn]);
        *(u16x8*)(wp + ((size_t)(ks * 8 + ng) * 64 + l) * 8) = val;
    }
}

// ---------------------------------------------------------------------------
// Kernel 2: projections v7 (unchanged — proven).
//   - x staged via LDS (fp16, XOR granule swizzle): coalesced global reads,
//     conflict-free ds_read_b128 A-frags.
//   - W streamed from wpack: contiguous 1KB wave fragments.
//   - q/k row-major epilogue; v fragment-packed vpack.
// ---------------------------------------------------------------------------
__global__ __launch_bounds__(256) void proj(
    const float* __restrict__ xq, const float* __restrict__ xk, const float* __restrict__ xv,
    const float* __restrict__ bq, const float* __restrict__ bk, const float* __restrict__ bv,
    const unsigned short* __restrict__ wpack,
    unsigned short* __restrict__ q_emb, unsigned short* __restrict__ k_emb,
    unsigned short* __restrict__ vpack) {
    __shared__ __align__(16) unsigned short xt[64 * 256];   // 32 KB fp16, swizzled
    const int mat = blockIdx.y;
    const float* x    = (mat == 0) ? xq : (mat == 1) ? xk : xv;
    const float* bias = (mat == 0) ? bq : (mat == 1) ? bk : bv;
    const unsigned short* wp = wpack + mat * 65536;

    const int tid = threadIdx.x;
    const int l = tid & 63, wv = tid >> 6;
    const int pair = wv >> 1, h = wv & 1;
    const int lm = l & 31, lh = l >> 5;
    const int row0 = blockIdx.x * 64;

    {
        const float* xb = x + (size_t)row0 * 256;
#pragma unroll
        for (int p = 0; p < 8; ++p) {
            const int idx = p * 256 + tid;       // 0..2047
            const int r = idx >> 5;              // row 0..63
            const int c8 = idx & 31;             // granule 0..31
            const float4* ap = (const float4*)(xb + r * 256 + c8 * 8);
            float4 a0 = ap[0], a1 = ap[1];
            u16x8 au;
            au[0] = f2h(a0.x); au[1] = f2h(a0.y); au[2] = f2h(a0.z); au[3] = f2h(a0.w);
            au[4] = f2h(a1.x); au[5] = f2h(a1.y); au[6] = f2h(a1.z); au[7] = f2h(a1.w);
            *(u16x8*)(xt + r * 256 + (c8 ^ (r & 31)) * 8) = au;
        }
    }
    __syncthreads();

    f32x16 acc[4];
#pragma unroll
    for (int i = 0; i < 4; ++i)
#pragma unroll
        for (int j = 0; j < 16; ++j) acc[i][j] = 0.0f;

#pragma unroll
    for (int ks = 0; ks < 16; ++ks) {
        f16x8 af = *(const f16x8*)(xt + (pair * 32 + lm) * 256 +
                                   (((ks * 2 + lh) ^ lm) * 8));
#pragma unroll
        for (int nt = 0; nt < 4; ++nt) {
            f16x8 bfr = *(const f16x8*)(wp + ((size_t)(ks * 8 + h * 4 + nt) * 64 + l) * 8);
            acc[nt] = __builtin_amdgcn_mfma_f32_32x32x16_f16(af, bfr, acc[nt], 0, 0, 0);
        }
    }

    if (mat < 2) {
        unsigned short* emb = (mat == 0) ? q_emb : k_emb;
#pragma unroll
        for (int nt = 0; nt < 4; ++nt) {
            const int n = h * 128 + nt * 32 + lm;
            const float bsv = bias[n];
#pragma unroll
            for (int r = 0; r < 16; ++r) {
                const int rl = (r & 3) + 8 * (r >> 2) + 4 * lh;
                emb[(size_t)(row0 + pair * 32 + rl) * 256 + n] = f2h(acc[nt][r] + bsv);
            }
        }
    } else {
        const int batch = row0 >> 13;
        const int m0 = (row0 & 8191) + pair * 32;   // v-row (k index) base
        unsigned short* vp = vpack + (size_t)batch * (512 * 8 * 64 * 8);
        const int base_kt = m0 >> 4;
#pragma unroll
        for (int nt = 0; nt < 4; ++nt) {
            const int dg = h * 4 + nt;              // d-group = n >> 5
            const int n = h * 128 + nt * 32 + lm;
            const float bsv = bias[n];
#pragma unroll
            for (int g = 0; g < 4; ++g) {
                u16x4 pk;
#pragma unroll
                for (int i = 0; i < 4; ++i) pk[i] = f2h(acc[nt][4 * g + i] + bsv);
                const int kt = base_kt + (g >> 1);
                const int lane = (g & 1) * 32 + lm;
                *(u16x4*)(vp + ((size_t)(kt * 8 + dg) * 64 + lane) * 8 + lh * 4) = pk;
            }
        }
    }
}

// ---------------------------------------------------------------------------
// Kernel 3: flash attention — the proven v7 kernel (best measured: 194 us),
// with one fix: LDS stats region properly sized (smax 1024 + ssum 1024 +
// alph 256 + linvb 256 = 2560B; previous builds declared only 2048B and
// alph/linvb accesses landed past the allocated array — harmless at
// 1 block/CU but out-of-bounds; now LDS_TOTAL = STAT_OFF + 4096).
//   - S-phase roles: wave (kq=wv>>1, pair=wv&1) computes 32k x 32q S^T tile.
//   - PV role: wave wv owns d-group dg = wv, O^T[32d x 64q], vf deduped.
//   - K staged via global_load_lds double buffer, source-side XOR swizzle.
//   - Barriers: plain __syncthreads (B3/B4).
// Session record (measured): lgkm-only barriers ±0 (v3); counted-vmcnt
// barriers +17us (v5); producer-consumer wave split +346us spill (v8);
// defer-max + tree-max +4us (v9).  Only traffic cuts won: V dedup (v6),
// vpack coalescing (v4), proj wpack/LDS staging (v7).
// ---------------------------------------------------------------------------
#define BN_ 128
#define NT_ (NK_ / BN_)                    // 64 iterations
#define KB_BYTES 65536                     // 128 rows x 512B (swizzled granules)
#define PSTRIDE 272                        // 64 rows x (256 + 16) : proven pad
#define PBYTES  (64 * PSTRIDE)             // 17408
#define STAT_OFF (2 * KB_BYTES + PBYTES)   // 148480
#define LDS_TOTAL (STAT_OFF + 4096)        // 152576 <= 160 KiB

__global__ __launch_bounds__(512, 2) void flash(
    const unsigned short* __restrict__ q_emb, const unsigned short* __restrict__ k_emb,
    const unsigned short* __restrict__ vpack, float* __restrict__ out) {
    __shared__ __align__(16) char lds_raw[LDS_TOTAL];
    char* pbuf = lds_raw + 2 * KB_BYTES;        // [64][272]
    float* smax = (float*)(lds_raw + STAT_OFF); // [64][4]
    float* ssum = smax + 256;                   // [64][4]
    float* alph = ssum + 256;                   // [64] per-q-row alpha
    float* linvb = alph + 64;                   // [64] per-q-row 1/l

    const int tid = threadIdx.x;
    const int l = tid & 63, wv = tid >> 6;      // wv 0..7
    const int kq = wv >> 1, pair = wv & 1;      // S-phase roles
    const int lm = l & 31, lh = l >> 5;

    const int bx = blockIdx.x;
    const int batch = bx >> 7;
    const int qb = (bx & 127) * 64;

    const unsigned short* kg = k_emb + (size_t)batch * NK_ * 256;
    const unsigned short* vp = vpack + (size_t)batch * (512 * 8 * 64 * 8);

    // Q fragments register-resident: q row = qb + pair*32 + lm, all 256 dims.
    const int mrow = batch * NQ_ + qb + pair * 32 + lm;
    f16x8 qf[16];
#pragma unroll
    for (int ks = 0; ks < 16; ++ks)
        qf[ks] = *(const f16x8*)(q_emb + (size_t)mrow * 256 + ks * 16 + lh * 8);

    // O^T accumulator (PV role): d rows = wv*32 + crow, q cols = qt*32 + lm.
    f32x16 oacc[2];
#pragma unroll
    for (int i = 0; i < 2; ++i)
#pragma unroll
        for (int j = 0; j < 16; ++j) oacc[i][j] = 0.0f;

    float mstat = -3.0e38f, lstat = 0.0f;

    // ---- K staging via global_load_lds ----
    const int rlane = l >> 5;                  // +0/+1 row within 1KB chunk
    const int gl = l & 31;                     // linear granule this lane fills
    auto stage_k = [&](int kb, char* kdst) {
#pragma unroll
        for (int p = 0; p < 8; ++p) {
            const int r0 = wv * 16 + 2 * p;            // wave-uniform base row
            const int r = r0 + rlane;
            const int gsw = gl ^ (r & 31);             // source granule
            const unsigned short* src = kg + (size_t)(kb + r) * 256 + gsw * 8;
            __builtin_amdgcn_global_load_lds(
                (const __attribute__((address_space(1))) void*)src,
                (__attribute__((address_space(3))) void*)(kdst + r0 * 512),
                16, 0, 0);
        }
    };

    // ---- V fragments direct-from-global, DEDUPED: dg = wv, 8 frags/wave.
    f16x8 vf[8];
    auto load_v = [&](int kb) {
        const size_t kt0 = (size_t)(kb >> 4);
#pragma unroll
        for (int ks2 = 0; ks2 < 8; ++ks2)
            vf[ks2] = *(const f16x8*)(vp + (((kt0 + ks2) * 8 + wv) * 64 + l) * 8);
    };

    // prologue: K tile 0 (full drain once)
    stage_k(0, lds_raw);
    __syncthreads();   // vmcnt(0) drain -> K tile 0 visible

    const int prow = pair * 32 + lm;  // this lane's S-role q row within block

    for (int t = 0; t < NT_; ++t) {
        const int kb = t * BN_;
        char* kcur = lds_raw + (t & 1) * KB_BYTES;
        // issue DMA for next K tile, then this tile's vf loads
        if (t + 1 < NT_) stage_k(kb + BN_, lds_raw + ((t + 1) & 1) * KB_BYTES);
        load_v(kb);

        // ---- S^T tile (32k x 32q): A = K rows kq*32+lm (swizzled), B = qf ----
        f32x16 s;
#pragma unroll
        for (int j = 0; j < 16; ++j) s[j] = 0.0f;
#pragma unroll
        for (int ks = 0; ks < 16; ++ks) {
            const int gsw = (2 * ks + lh) ^ lm;   // 32 lanes -> 32 distinct granules
            f16x8 kf = *(const f16x8*)(kcur + (kq * 32 + lm) * 512 + gsw * 16);
            s = __builtin_amdgcn_mfma_f32_32x32x16_f16(kf, qf[ks], s, 0, 0, 0);
        }

        // ---- partial max over this wave's 32 k (per lane: q = lm) ----
        float pm = s[0];
#pragma unroll
        for (int j = 1; j < 16; ++j) pm = fmaxf(pm, s[j]);
        pm = fmaxf(pm, __shfl_xor(pm, 32, 64));
        if (lh == 0) smax[prow * 4 + kq] = pm;
        __syncthreads();   // B3: partial maxes visible

        const float4 m4 = *(const float4*)&smax[prow * 4];
        const float gm = fmaxf(fmaxf(m4.x, m4.y), fmaxf(m4.z, m4.w));
        const float mn = fmaxf(mstat, gm);
        const float alpha = __expf(mstat - mn);
        mstat = mn;
        if (kq == 0 && lh == 0) alph[prow] = alpha;   // publish per-q-row alpha

        // ---- exp (fp16-rounded for num/denom consistency), write P^T tile,
        //      partial sum ----
        float psum = 0.0f;
#pragma unroll
        for (int g = 0; g < 4; ++g) {
            u16x4 pk;
#pragma unroll
            for (int j = 0; j < 4; ++j) {
                const unsigned short hh = f2h(__expf(s[g * 4 + j] - mn));
                pk[j] = hh;
                psum += h2f(hh);
            }
            *(u16x4*)(pbuf + prow * PSTRIDE + (kq * 32 + 8 * g + 4 * lh) * 2) = pk;
        }
        psum += __shfl_xor(psum, 32, 64);
        if (lh == 0) ssum[prow * 4 + kq] = psum;
        __syncthreads();   // B4: P tiles + partial sums + alph visible

        const float4 s4 = *(const float4*)&ssum[prow * 4];
        lstat = lstat * alpha + (s4.x + s4.y) + (s4.z + s4.w);

        // ---- rescale O by per-q-row alpha (cols q = qt*32 + lm) ----
        const float a0 = alph[lm];
        const float a1 = alph[lm + 32];
#pragma unroll
        for (int j = 0; j < 16; ++j) oacc[0][j] *= a0;
#pragma unroll
        for (int j = 0; j < 16; ++j) oacc[1][j] *= a1;

        // ---- O^T += V^T P^T : A = vf (dg = wv, registers), B = P frags for
        //      both q-tiles from LDS ----
#pragma unroll
        for (int ks2 = 0; ks2 < 8; ++ks2) {
            const f16x8 vfr = vf[ks2];
            f16x8 pf0 = *(const f16x8*)(pbuf + lm * PSTRIDE + ks2 * 32 + lh * 16);
            f16x8 pf1 = *(const f16x8*)(pbuf + (lm + 32) * PSTRIDE + ks2 * 32 + lh * 16);
            oacc[0] = __builtin_amdgcn_mfma_f32_32x32x16_f16(vfr, pf0, oacc[0], 0, 0, 0);
            oacc[1] = __builtin_amdgcn_mfma_f32_32x32x16_f16(vfr, pf1, oacc[1], 0, 0, 0);
        }
    }

    // ---- publish per-q-row 1/l, then write out[b][q][d] fp32 ----
    if (kq == 0 && lh == 0) linvb[prow] = 1.0f / lstat;
    __syncthreads();
    const float linv0 = linvb[lm];
    const float linv1 = linvb[lm + 32];
#pragma unroll
    for (int qt = 0; qt < 2; ++qt) {
        const float lv = qt ? linv1 : linv0;
        float* orow = out + (size_t)(batch * NQ_ + qb + qt * 32 + lm) * 256 + wv * 32;
#pragma unroll
        for (int g = 0; g < 4; ++g) {
            float4 o4;
            o4.x = oacc[qt][4 * g + 0] * lv;
            o4.y = oacc[qt][4 * g + 1] * lv;
            o4.z = oacc[qt][4 * g + 2] * lv;
            o4.w = oacc[qt][4 * g + 3] * lv;
            *(float4*)(orow + 8 * g + 4 * lh) = o4;
        }
    }
}

// ---------------------------------------------------------------------------
extern "C" void kernel_launch(void* const* d_in, const int* in_sizes, int n_in,
                              void* d_out, int out_size, void* d_ws, size_t ws_size,
                              hipStream_t stream) {
    const float* q  = (const float*)d_in[0];
    const float* k  = (const float*)d_in[1];
    const float* v  = (const float*)d_in[2];
    const float* Wq = (const float*)d_in[3];
    const float* bq = (const float*)d_in[4];
    const float* Wk = (const float*)d_in[5];
    const float* bk = (const float*)d_in[6];
    const float* Wv = (const float*)d_in[7];
    const float* bv = (const float*)d_in[8];
    float* out = (float*)d_out;

    unsigned short* wpack   = (unsigned short*)d_ws;          // 3 * 65536 fp16
    unsigned short* q_emb   = wpack + 3 * 65536;              // [16384][256]
    unsigned short* k_emb   = q_emb + (size_t)M_ * DH_;       // [16384][256]
    unsigned short* vpack   = k_emb + (size_t)M_ * DH_;       // [2][512][8][64][8]

    wt_conv<<<dim3(4, 4, 3), 256, 0, stream>>>(Wq, Wk, Wv, wpack);
    proj<<<dim3(256, 3), 256, 0, stream>>>(q, k, v, bq, bk, bv, wpack, q_emb, k_emb, vpack);
    flash<<<256, 512, 0, stream>>>(q_emb, k_emb, vpack, out);
}